// Round 5
// baseline (320.990 us; speedup 1.0000x reference)
//
#include <hip/hip_runtime.h>

// out[t,c] = bias[c] + sum_{k=0..99} w_norm[k,c] * x[t+k-99, c]   (x zero-padded t<0)
// T=16384, NC=2048, FW=100, all float32.
// Channel-major LDS ring (ds_read_b128) for x AND weights; both row strides are
// odd multiples of 4 dwords (292, 108) -> conflict-free b128 (proved R4: 0 conflicts).
// Weights normalized per-thread in registers (prologue), stored once to LDS,
// re-read per K-chunk into a fixed wk[8] quad pair (no spills: ~100 VGPR live).

#define T_TOT 16384
#define NCH   2048
#define FW    100
#define CB    32          // channels per block
#define TB    128         // time steps per chunk
#define NTHR  256
#define ROWL  292         // ring row stride (floats): 256 + 36 pad; 292 = 4*73 (odd*4)
#define WROW  108         // weight row stride: 104 taps + 4 pad; 108 = 4*27 (odd*4)
#define NSEG  12          // 64 cgroups * 12 = 768 blocks = exactly 3/CU (LDS-limited)
#define NCHUNK_TOT (T_TOT / TB)   // 128

// One K-chunk of 8 taps (taps j = KI*8 .. KI*8+7 of the 104-tap shifted filter):
// load 8 new x floats into window slots NS..NS+7, 8 weights, 128 FMAs at phase PH.
#define KC_STEP(KI, PH, NS) do {                                                \
    int ro_ = (base0 + (KI)*8 + 16) & 255;                                      \
    float4 n0_ = *(const float4*)(rrow + ro_);                                  \
    float4 n1_ = *(const float4*)(rrow + ro_ + 4);                              \
    float4 w0_ = *(const float4*)(wrow + (KI)*8);                               \
    float4 w1_ = *(const float4*)(wrow + (KI)*8 + 4);                           \
    xw[(NS)+0]=n0_.x; xw[(NS)+1]=n0_.y; xw[(NS)+2]=n0_.z; xw[(NS)+3]=n0_.w;     \
    xw[(NS)+4]=n1_.x; xw[(NS)+5]=n1_.y; xw[(NS)+6]=n1_.z; xw[(NS)+7]=n1_.w;     \
    float wk_[8];                                                               \
    wk_[0]=w0_.x; wk_[1]=w0_.y; wk_[2]=w0_.z; wk_[3]=w0_.w;                     \
    wk_[4]=w1_.x; wk_[5]=w1_.y; wk_[6]=w1_.z; wk_[7]=w1_.w;                     \
    _Pragma("unroll")                                                           \
    for (int u_ = 0; u_ < 8; ++u_) {                                            \
      _Pragma("unroll")                                                         \
      for (int i_ = 0; i_ < 16; ++i_)                                           \
        acc[i_] = fmaf(wk_[u_], xw[((PH) + u_ + i_) % 24], acc[i_]);            \
    }                                                                           \
} while (0)

__global__ __launch_bounds__(NTHR, 3)
void catent_fir(const float* __restrict__ x,
                const float* __restrict__ wraw,
                const float* __restrict__ bias,
                float* __restrict__ out) {
    __shared__ __align__(16) float ring[CB * ROWL];   // 37376 B, ring[c*ROWL + (t&255)]
    __shared__ __align__(16) float wl[CB * WROW];     // 13824 B, wl[c*WROW + j], j=0..103

    const int tid   = threadIdx.x;
    const int cgrp  = blockIdx.x & 63;
    const int sidx  = blockIdx.x >> 6;          // 0..NSEG-1
    const int cbase = cgrp * CB;

    const int ch0 = (sidx * NCHUNK_TOT) / NSEG;
    const int ch1 = ((sidx + 1) * NCHUNK_TOT) / NSEG;
    const int tseg0 = ch0 * TB;

    const int c = tid & 31;
    const int g = tid >> 5;              // 0..7 time groups

    // ---- weights: every thread normalizes its channel in registers; g==0 writes LDS ----
    // layout: w'[0]=0, w'[j]=relu(w[j-1][c])*scl for j=1..100, w'[101..103]=0
    {
        const float* wcol = wraw + cbase + c;
        float wt[104];
        float s = 0.0f;
        wt[0] = 0.0f;
        #pragma unroll
        for (int j = 1; j <= FW; ++j) {
            float v = fmaxf(wcol[(size_t)(j - 1) * NCH], 0.0f);
            wt[j] = v;
            s = fmaf(v, v, s);
        }
        wt[101] = 0.0f; wt[102] = 0.0f; wt[103] = 0.0f;
        float scl = rsqrtf(fmaxf(s, 1e-12f));
        if (g == 0) {
            float* wr = &wl[c * WROW];
            #pragma unroll
            for (int q = 0; q < 26; ++q)
                *(float4*)(wr + q * 4) = make_float4(wt[q*4] * scl, wt[q*4+1] * scl,
                                                    wt[q*4+2] * scl, wt[q*4+3] * scl);
        }
    }

    // ---- prologue: stage times [tseg0-128, tseg0+127]; mirror slots [0,32) -> [256,288) ----
    {
        float* rw = &ring[c * ROWL];
        for (int p = 0; p < 2; ++p) {
            int tbase = tseg0 - TB + p * TB + g * 16;
            float v[16];
            #pragma unroll
            for (int j = 0; j < 16; ++j) {
                int t = tbase + j;
                v[j] = (t >= 0) ? x[(size_t)t * NCH + cbase + c] : 0.0f;
            }
            int rm = tbase & 255;
            #pragma unroll
            for (int q = 0; q < 4; ++q)
                *(float4*)(rw + rm + q * 4) = make_float4(v[q*4], v[q*4+1], v[q*4+2], v[q*4+3]);
            if (rm < 32) {
                #pragma unroll
                for (int q = 0; q < 4; ++q)
                    *(float4*)(rw + 256 + rm + q * 4) = make_float4(v[q*4], v[q*4+1], v[q*4+2], v[q*4+3]);
            }
        }
    }
    __syncthreads();   // covers weight LDS writes + x prologue staging

    const float biasr = bias[cbase + c];
    const float* rrow = &ring[c * ROWL];
    const float* wrow = &wl[c * WROW];
    float* rwr = &ring[c * ROWL];

    for (int ch = ch0; ch < ch1; ++ch) {
        const int t0 = ch * TB;
        const bool do_stage = (ch + 1 < ch1);

        // T14: issue next-chunk global loads early; ds_write after the drain barrier
        float stv[16];
        if (do_stage) {
            const size_t gb = (size_t)(t0 + TB + g * 16) * NCH + cbase + c;
            #pragma unroll
            for (int j = 0; j < 16; ++j) stv[j] = x[gb + (size_t)j * NCH];
        }

        float acc[16];
        #pragma unroll
        for (int i = 0; i < 16; ++i) acc[i] = biasr;

        float xw[24];
        const int base0 = t0 + g * 16 - 100;     // multiple of 4 => 16B-aligned ring reads

        // kc = 0: fill window x[base0 .. base0+23], taps j=0..7 (w'[0]=0)
        {
            int ro = base0 & 255;
            #pragma unroll
            for (int q = 0; q < 6; ++q) {
                float4 v = *(const float4*)(rrow + ro + q * 4);
                xw[q*4+0] = v.x; xw[q*4+1] = v.y; xw[q*4+2] = v.z; xw[q*4+3] = v.w;
            }
            float4 w0 = *(const float4*)(wrow);
            float4 w1 = *(const float4*)(wrow + 4);
            float wk[8];
            wk[0]=w0.x; wk[1]=w0.y; wk[2]=w0.z; wk[3]=w0.w;
            wk[4]=w1.x; wk[5]=w1.y; wk[6]=w1.z; wk[7]=w1.w;
            #pragma unroll
            for (int u = 0; u < 8; ++u) {
                #pragma unroll
                for (int i = 0; i < 16; ++i)
                    acc[i] = fmaf(wk[u], xw[(u + i) % 24], acc[i]);
            }
        }

        // kc = 1..12: slide by 8 (register rotation, phase period 3).
        // Taps 101..103 are zero; their (stale but finite) x reads contribute 0.
        KC_STEP(1,  8, 0);
        KC_STEP(2, 16, 8);
        KC_STEP(3,  0, 16);
        KC_STEP(4,  8, 0);
        KC_STEP(5, 16, 8);
        KC_STEP(6,  0, 16);
        KC_STEP(7,  8, 0);
        KC_STEP(8, 16, 8);
        KC_STEP(9,  0, 16);
        KC_STEP(10, 8, 0);
        KC_STEP(11,16, 8);
        KC_STEP(12, 0, 16);

        __syncthreads();   // all ring reads of this chunk done

        if (do_stage) {
            int rm = (t0 + TB + g * 16) & 255;
            #pragma unroll
            for (int q = 0; q < 4; ++q)
                *(float4*)(rwr + rm + q * 4) = make_float4(stv[q*4], stv[q*4+1], stv[q*4+2], stv[q*4+3]);
            if (rm < 32) {
                #pragma unroll
                for (int q = 0; q < 4; ++q)
                    *(float4*)(rwr + 256 + rm + q * 4) = make_float4(stv[q*4], stv[q*4+1], stv[q*4+2], stv[q*4+3]);
            }
        }
        __syncthreads();   // staged rows visible for next chunk

        // stores last: they drain during the next chunk's compute, not at a barrier
        {
            size_t ob = (size_t)(t0 + g * 16) * NCH + cbase + c;
            #pragma unroll
            for (int i = 0; i < 16; ++i) out[ob + (size_t)i * NCH] = acc[i];
        }
    }
}

extern "C" void kernel_launch(void* const* d_in, const int* in_sizes, int n_in,
                              void* d_out, int out_size, void* d_ws, size_t ws_size,
                              hipStream_t stream) {
    const float* x    = (const float*)d_in[0];   // [T, NC]
    const float* wraw = (const float*)d_in[1];   // [FW, NC]
    const float* bias = (const float*)d_in[2];   // [1, NC]
    float* out = (float*)d_out;                  // [T, NC]

    dim3 grid(64 * NSEG);   // 768 blocks = exactly 3/CU
    dim3 block(NTHR);
    catent_fir<<<grid, block, 0, stream>>>(x, wraw, bias, out);
}